// Round 5
// baseline (140.251 us; speedup 1.0000x reference)
//
#include <hip/hip_runtime.h>
#include <math.h>

#define B_TOT 2048
#define IN_TOT 512
#define OUT_TOT 512
#define CPB 8             // cols per block
#define RPB 256           // rows per block (32 ty-slots x m=8)
#define M 8               // rows per thread
#define NQ 128            // k-quads (512 k / 4)

__global__ __launch_bounds__(256, 4) void morph_kernel(
    const float* __restrict__ x,
    const float* __restrict__ wdil,
    const float* __restrict__ wero,
    float* __restrict__ out)
{
    // [arr][col*512 + phys_quad*4 + e] : 2 * 8 cols * 512 k * 4B = 32 KB
    // staged ONCE; no barriers in the main loop. 4-5 blocks/CU.
    __shared__ float w_s[2][CPB * IN_TOT];

    const int tid = (int)threadIdx.x;
    const int tx  = tid & 7;      // col within block
    const int ty  = tid >> 3;     // row slot: rows ty + 32*mi

    const int col0 = (int)blockIdx.x * CPB;
    const int row0 = (int)blockIdx.y * RPB;

    // ---- stage weights, source-side quad-XOR swizzle (involution in low 3 bits) ----
    // phys quad p of col c holds logical quad l = (p & ~7) | ((p ^ c) & 7)
#pragma unroll
    for (int i = 0; i < 4; ++i) {
        const int s  = i * 256 + tid;           // quad slot in [0, 1024)
        const int c  = s >> 7;
        const int qp = s & 127;
        const int ql = (qp & ~7) | ((qp ^ c) & 7);
        const int g  = (col0 + c) * IN_TOT + ql * 4;
        *(float4*)&w_s[0][s * 4] = *(const float4*)(wdil + g);
        *(float4*)&w_s[1][s * 4] = *(const float4*)(wero + g);
    }
    __syncthreads();   // the only barrier

    float dil[M], ero[M];
#pragma unroll
    for (int mi = 0; mi < M; ++mi) { dil[mi] = -INFINITY; ero[mi] = INFINITY; }

    const float* xr[M];
#pragma unroll
    for (int mi = 0; mi < M; ++mi)
        xr[mi] = x + (size_t)(row0 + ty + 32 * mi) * IN_TOT;

    const float* __restrict__ wdp = &w_s[0][tx * IN_TOT];
    const float* __restrict__ wep = &w_s[1][tx * IN_TOT];

#pragma unroll 1
    for (int hi = 0; hi < 8; ++hi) {
#pragma unroll
        for (int lo = 0; lo < 16; ++lo) {
            const int q  = hi * 16 + lo;
            const int ph = (q & ~7) | ((q ^ tx) & 7);   // conflict-free (8 groups x 8-bcast)
            float4 wd4 = *(const float4*)(wdp + ph * 4);
            float4 we4 = *(const float4*)(wep + ph * 4);
            const int k4 = q * 4;
#pragma unroll
            for (int mi = 0; mi < M; ++mi) {
                float4 xv = *(const float4*)(xr[mi] + k4);  // 8-lane broadcast, L1-hot
                dil[mi] = fmaxf(fmaxf(xv.x + wd4.x, xv.y + wd4.y), dil[mi]);
                dil[mi] = fmaxf(fmaxf(xv.z + wd4.z, xv.w + wd4.w), dil[mi]);
                ero[mi] = fminf(fminf(xv.x - we4.x, xv.y - we4.y), ero[mi]);
                ero[mi] = fminf(fminf(xv.z - we4.z, xv.w - we4.w), ero[mi]);
            }
        }
    }

    float* op = out + (size_t)(row0 + ty) * OUT_TOT + col0 + tx;
#pragma unroll
    for (int mi = 0; mi < M; ++mi)
        op[(size_t)32 * mi * OUT_TOT] = dil[mi] + ero[mi];
}

extern "C" void kernel_launch(void* const* d_in, const int* in_sizes, int n_in,
                              void* d_out, int out_size, void* d_ws, size_t ws_size,
                              hipStream_t stream)
{
    const float* x  = (const float*)d_in[0];
    const float* wd = (const float*)d_in[1];
    const float* we = (const float*)d_in[2];
    float* out = (float*)d_out;

    dim3 grid(OUT_TOT / CPB, B_TOT / RPB);   // (64, 8) = 512 blocks
    dim3 block(256);
    hipLaunchKernelGGL(morph_kernel, grid, block, 0, stream, x, wd, we, out);
}

// Round 6
// 67.419 us; speedup vs baseline: 2.0803x; 2.0803x over previous
//
#include <hip/hip_runtime.h>
#include <math.h>

#define B_TOT 2048
#define IN_TOT 512
#define OUT_TOT 512
#define CPB 8             // cols per block
#define RPB 128           // rows per block (32 ty-slots x m=4)
#define M 4               // rows per thread
#define NQ 128            // k-quads

__global__ __launch_bounds__(256, 4) void morph_kernel(
    const float* __restrict__ x,
    const float* __restrict__ wdil,
    const float* __restrict__ wero,
    float* __restrict__ out)
{
    // [arr][col*512 + phys_quad*4 + e] : 2 * 8 cols * 512 k * 4B = 32 KB
    // staged ONCE; no barriers in the main loop.
    __shared__ float w_s[2][CPB * IN_TOT];

    const int tid = (int)threadIdx.x;
    const int tx  = tid & 7;      // col within block
    const int ty  = tid >> 3;     // row slot (0..31): rows ty + 32*mi

    const int col0 = (int)blockIdx.x * CPB;
    const int row0 = (int)blockIdx.y * RPB;

    // ---- stage weights, source-side quad-XOR swizzle (involution, low 3 bits) ----
    // phys quad p of col c holds logical quad l = (p & ~7) | ((p ^ c) & 7)
#pragma unroll
    for (int i = 0; i < 4; ++i) {
        const int s  = i * 256 + tid;           // quad slot in [0, 1024)
        const int c  = s >> 7;
        const int qp = s & 127;
        const int ql = (qp & ~7) | ((qp ^ c) & 7);
        const int g  = (col0 + c) * IN_TOT + ql * 4;
        *(float4*)&w_s[0][s * 4] = *(const float4*)(wdil + g);
        *(float4*)&w_s[1][s * 4] = *(const float4*)(wero + g);
    }
    __syncthreads();   // the only barrier

    float dil[M], ero[M];
#pragma unroll
    for (int mi = 0; mi < M; ++mi) { dil[mi] = -INFINITY; ero[mi] = INFINITY; }

    const float* xr = x + (size_t)(row0 + ty) * IN_TOT;   // rows stride 32*IN_TOT per mi

    const float* __restrict__ wdp = &w_s[0][tx * IN_TOT];
    const float* __restrict__ wep = &w_s[1][tx * IN_TOT];

#pragma unroll 4
    for (int q = 0; q < NQ; ++q) {
        const int ph = (q & ~7) | ((q ^ tx) & 7);   // swizzled: 8 groups x 8-bcast, free
        float4 wd4 = *(const float4*)(wdp + ph * 4);
        float4 we4 = *(const float4*)(wep + ph * 4);

        // batch the 4 independent x loads (ILP), then compute
        float4 xv[M];
#pragma unroll
        for (int mi = 0; mi < M; ++mi)
            xv[mi] = *(const float4*)(xr + (size_t)(32 * mi) * IN_TOT + q * 4);

#pragma unroll
        for (int mi = 0; mi < M; ++mi) {
            dil[mi] = fmaxf(fmaxf(xv[mi].x + wd4.x, xv[mi].y + wd4.y), dil[mi]);
            dil[mi] = fmaxf(fmaxf(xv[mi].z + wd4.z, xv[mi].w + wd4.w), dil[mi]);
            ero[mi] = fminf(fminf(xv[mi].x - we4.x, xv[mi].y - we4.y), ero[mi]);
            ero[mi] = fminf(fminf(xv[mi].z - we4.z, xv[mi].w - we4.w), ero[mi]);
        }
    }

    float* op = out + (size_t)(row0 + ty) * OUT_TOT + col0 + tx;
#pragma unroll
    for (int mi = 0; mi < M; ++mi)
        op[(size_t)32 * mi * OUT_TOT] = dil[mi] + ero[mi];
}

extern "C" void kernel_launch(void* const* d_in, const int* in_sizes, int n_in,
                              void* d_out, int out_size, void* d_ws, size_t ws_size,
                              hipStream_t stream)
{
    const float* x  = (const float*)d_in[0];
    const float* wd = (const float*)d_in[1];
    const float* we = (const float*)d_in[2];
    float* out = (float*)d_out;

    dim3 grid(OUT_TOT / CPB, B_TOT / RPB);   // (64, 16) = 1024 blocks = 4/CU
    dim3 block(256);
    hipLaunchKernelGGL(morph_kernel, grid, block, 0, stream, x, wd, we, out);
}